// Round 3
// baseline (3887.467 us; speedup 1.0000x reference)
//
#include <hip/hip_runtime.h>
#include <math.h>

// RNN scan: h_t = tanh(h_{t-1} @ Whh + b_hh + x_t * Wxh + b_xh), out = h_T @ Wout + b_out
// B=16384 rows, T=1024 steps, H=32 hidden.
//
// Design (round 3): DPP-systolic fp32 — no LDS anywhere.
//  - each 16-lane DPP row owns one batch row; lane p holds h_p and h_{p+16}.
//  - dot product via row_ror:k DPP rotations (k=0..15). ISA semantics
//    (verified vs AMD's DPP prefix-scan idiom): row_ror:K -> dst lane i gets
//    src lane (i-K)&15. Weights preloaded per-lane to match (64 VGPRs).
//  - x read directly from global with a 4-step float4 register prefetch
//    (16 lanes share one address -> one transaction, L2-resident).
//  - 1024 blocks x 256 thr = 4096 waves (4/SIMD), 16 rows/block.

constexpr int Tlen = 1024;
constexpr int Hdim = 32;
constexpr int NBLOCKS = 1024;

__device__ __forceinline__ float fast_tanh(float x) {
    // tanh(x) = sign(x) * (1 - e) / (1 + e),  e = exp(-2|x|); e underflows to 0
    // for large |x| -> result +/-1 exactly. approx err ~1e-6.
    float ax = __builtin_fabsf(x);
    float e  = __builtin_amdgcn_exp2f(ax * -2.8853900817779268f); // exp(-2ax)
    float num = 1.0f - e;
    float den = 1.0f + e;
    float r = num * __builtin_amdgcn_rcpf(den);
    return __builtin_copysignf(r, x);
}

// row_ror:K within 16-lane DPP row: dst lane i gets src lane (i-K)&15.
template <int CTRL>
__device__ __forceinline__ float ror16(float v) {
    int iv = __builtin_bit_cast(int, v);
    int r = __builtin_amdgcn_update_dpp(iv, iv, CTRL, 0xF, 0xF, true);
    return __builtin_bit_cast(float, r);
}

__global__ __launch_bounds__(256, 4)
void rnn_dpp_kernel(const float* __restrict__ x,    // [B,T]
                    const float* __restrict__ Wxh,  // [1,H]
                    const float* __restrict__ b_xh, // [H]
                    const float* __restrict__ Whh,  // [H,H] row-major (i,j)
                    const float* __restrict__ b_hh, // [H]
                    const float* __restrict__ Wout, // [H,1]
                    const float* __restrict__ b_out,// [1]
                    float* __restrict__ out)        // [B,1]
{
    const int tid = threadIdx.x;
    const int p   = tid & 15;                 // lane within DPP row
    const int grp = tid >> 4;                 // 16 batch rows per block
    const int row = blockIdx.x * 16 + grp;
    const float* xr = x + (size_t)row * Tlen;

    // Weight preload in rotation order. At slot k, row_ror:k delivers
    // h_m with m = (p-k)&15 (and h_{m+16} from the second register). Lane p
    // accumulates outputs p and p+16, so it needs Whh[m][p], Whh[m+16][p],
    // Whh[m][p+16], Whh[m+16][p+16].  64 VGPRs, loaded once.
    float wa1[16], wa2[16], wb1[16], wb2[16];
    #pragma unroll
    for (int k = 0; k < 16; ++k) {
        const int m = (p - k) & 15;
        wa1[k] = Whh[m * Hdim + p];
        wa2[k] = Whh[(m + 16) * Hdim + p];
        wb1[k] = Whh[m * Hdim + (p + 16)];
        wb2[k] = Whh[(m + 16) * Hdim + (p + 16)];
    }
    const float ba  = b_hh[p]      + b_xh[p];
    const float bb  = b_hh[p + 16] + b_xh[p + 16];
    const float wxa = Wxh[p];
    const float wxb = Wxh[p + 16];

    float h1 = 0.0f, h2 = 0.0f;               // h_p, h_{p+16} of this batch row
    float4 xq = *(const float4*)xr;           // current 4-step x chunk

    #pragma unroll 1
    for (int tc = 0; tc < Tlen; tc += 4) {
        // prefetch next chunk (clamped on last iter; value unused then)
        const int tn = (tc + 4 < Tlen) ? (tc + 4) : tc;
        float4 xn = *(const float4*)(xr + tn);
        const float xsv[4] = {xq.x, xq.y, xq.z, xq.w};

        #pragma unroll
        for (int u = 0; u < 4; ++u) {
            float a1 = fmaf(xsv[u], wxa, ba);   // output column p
            float b1 = fmaf(xsv[u], wxb, bb);   // output column p+16
            float a2 = 0.0f, b2 = 0.0f;
            // k = 0: no rotation
            a1 = fmaf(h1, wa1[0], a1);  a2 = fmaf(h2, wa2[0], a2);
            b1 = fmaf(h1, wb1[0], b1);  b2 = fmaf(h2, wb2[0], b2);
            // k = 1..15: independent rotations of the ORIGINAL h (max ILP)
            #define RNN_STEP(K)                                          \
            {                                                            \
                float r1 = ror16<0x120 + K>(h1);                         \
                float r2 = ror16<0x120 + K>(h2);                         \
                a1 = fmaf(r1, wa1[K], a1);  a2 = fmaf(r2, wa2[K], a2);   \
                b1 = fmaf(r1, wb1[K], b1);  b2 = fmaf(r2, wb2[K], b2);   \
            }
            RNN_STEP(1)  RNN_STEP(2)  RNN_STEP(3)  RNN_STEP(4)
            RNN_STEP(5)  RNN_STEP(6)  RNN_STEP(7)  RNN_STEP(8)
            RNN_STEP(9)  RNN_STEP(10) RNN_STEP(11) RNN_STEP(12)
            RNN_STEP(13) RNN_STEP(14) RNN_STEP(15)
            #undef RNN_STEP
            h1 = fast_tanh(a1 + a2);
            h2 = fast_tanh(b1 + b2);
        }
        xq = xn;
    }

    // out[row] = sum_p (h1*Wout[p] + h2*Wout[p+16]) + b_out, reduced over the
    // 16-lane group (xor offsets 1,2,4,8 stay inside the group).
    float v = fmaf(h1, Wout[p], h2 * Wout[p + 16]);
    v += __shfl_xor(v, 1, 64);
    v += __shfl_xor(v, 2, 64);
    v += __shfl_xor(v, 4, 64);
    v += __shfl_xor(v, 8, 64);
    if (p == 0) out[row] = v + b_out[0];
}

extern "C" void kernel_launch(void* const* d_in, const int* in_sizes, int n_in,
                              void* d_out, int out_size, void* d_ws, size_t ws_size,
                              hipStream_t stream) {
    const float* x     = (const float*)d_in[0];
    const float* Wxh   = (const float*)d_in[1];
    const float* b_xh  = (const float*)d_in[2];
    const float* Whh   = (const float*)d_in[3];
    const float* b_hh  = (const float*)d_in[4];
    const float* Wout  = (const float*)d_in[5];
    const float* b_out = (const float*)d_in[6];
    float* out = (float*)d_out;

    rnn_dpp_kernel<<<NBLOCKS, 256, 0, stream>>>(x, Wxh, b_xh, Whh, b_hh, Wout,
                                                b_out, out);
}

// Round 4
// 3872.387 us; speedup vs baseline: 1.0039x; 1.0039x over previous
//
#include <hip/hip_runtime.h>
#include <math.h>

// RNN scan: h_t = tanh(h_{t-1} @ Whh + b_hh + x_t * Wxh + b_xh), out = h_T @ Wout + b_out
// B=16384 rows, T=1024 steps, H=32 hidden.
//
// Design (round 4): DPP-systolic fp32, weights in FORCED registers.
//  - each 16-lane DPP row owns one batch row; lane p holds h_p and h_{p+16}.
//  - dot product via row_ror:k DPP (k=0..15): dst lane i gets src lane (i-k)&15
//    (verified by R3 correctness pass).
//  - R3 lesson: private arrays indexed by a loop variable are NEVER promoted
//    to VGPRs (SROA runs before unroll) -> they lived in scratch, 12.7 GB HBM
//    traffic, VALUBusy 15%. Fix: 64 macro-generated scalar consts (DECLW),
//    literal indices only. Same for the 4-step x temp (explicit expansion).
//  - x read from global, 4-step float4 register prefetch (16 lanes share one
//    address -> one transaction, L2-resident).
//  - 1024 blocks x 256 thr = 4096 waves (4/SIMD), 16 rows/block.

constexpr int Tlen = 1024;
constexpr int Hdim = 32;
constexpr int NBLOCKS = 1024;

__device__ __forceinline__ float fast_tanh(float x) {
    // tanh(x) = sign(x) * (1 - e) / (1 + e),  e = exp(-2|x|); e underflows to 0
    // for large |x| -> result +/-1 exactly. approx err ~1e-6.
    float ax = __builtin_fabsf(x);
    float e  = __builtin_amdgcn_exp2f(ax * -2.8853900817779268f); // exp(-2ax)
    float num = 1.0f - e;
    float den = 1.0f + e;
    float r = num * __builtin_amdgcn_rcpf(den);
    return __builtin_copysignf(r, x);
}

// row_ror:K within 16-lane DPP row: dst lane i gets src lane (i-K)&15.
template <int CTRL>
__device__ __forceinline__ float ror16(float v) {
    int iv = __builtin_bit_cast(int, v);
    int r = __builtin_amdgcn_update_dpp(iv, iv, CTRL, 0xF, 0xF, true);
    return __builtin_bit_cast(float, r);
}

__global__ __launch_bounds__(256, 4)
void rnn_dpp_kernel(const float* __restrict__ x,    // [B,T]
                    const float* __restrict__ Wxh,  // [1,H]
                    const float* __restrict__ b_xh, // [H]
                    const float* __restrict__ Whh,  // [H,H] row-major (i,j)
                    const float* __restrict__ b_hh, // [H]
                    const float* __restrict__ Wout, // [H,1]
                    const float* __restrict__ b_out,// [1]
                    float* __restrict__ out)        // [B,1]
{
    const int tid = threadIdx.x;
    const int p   = tid & 15;                 // lane within DPP row
    const int grp = tid >> 4;                 // 16 batch rows per block
    const int row = blockIdx.x * 16 + grp;
    const float* xr = x + (size_t)row * Tlen;

    // Weight preload, rotation order: at slot K, row_ror:K delivers h_m with
    // m=(p-K)&15 (and h_{m+16}). Lane p accumulates outputs p and p+16.
    // 64 named scalars -> guaranteed VGPR residency (no SROA dependence).
#define DECLW(K)                                                          \
    const float wa1_##K = Whh[(((p - K) & 15)     ) * Hdim + p     ];     \
    const float wa2_##K = Whh[(((p - K) & 15) + 16) * Hdim + p     ];     \
    const float wb1_##K = Whh[(((p - K) & 15)     ) * Hdim + p + 16];     \
    const float wb2_##K = Whh[(((p - K) & 15) + 16) * Hdim + p + 16];
    DECLW(0)  DECLW(1)  DECLW(2)  DECLW(3)
    DECLW(4)  DECLW(5)  DECLW(6)  DECLW(7)
    DECLW(8)  DECLW(9)  DECLW(10) DECLW(11)
    DECLW(12) DECLW(13) DECLW(14) DECLW(15)
#undef DECLW

    const float ba  = b_hh[p]      + b_xh[p];
    const float bb  = b_hh[p + 16] + b_xh[p + 16];
    const float wxa = Wxh[p];
    const float wxb = Wxh[p + 16];

    float h1 = 0.0f, h2 = 0.0f;               // h_p, h_{p+16} of this batch row
    float4 xq = *(const float4*)xr;           // current 4-step x chunk

#define RNN_K(K)                                                          \
    {                                                                     \
        float r1 = ror16<0x120 + K>(h1);                                  \
        float r2 = ror16<0x120 + K>(h2);                                  \
        a1 = fmaf(r1, wa1_##K, a1);  a2 = fmaf(r2, wa2_##K, a2);          \
        b1 = fmaf(r1, wb1_##K, b1);  b2 = fmaf(r2, wb2_##K, b2);          \
    }
#define DO_STEP(XV)                                                       \
    {                                                                     \
        float a1 = fmaf((XV), wxa, ba);                                   \
        float b1 = fmaf((XV), wxb, bb);                                   \
        float a2 = 0.0f, b2 = 0.0f;                                       \
        a1 = fmaf(h1, wa1_0, a1);  a2 = fmaf(h2, wa2_0, a2);              \
        b1 = fmaf(h1, wb1_0, b1);  b2 = fmaf(h2, wb2_0, b2);              \
        RNN_K(1)  RNN_K(2)  RNN_K(3)  RNN_K(4)                            \
        RNN_K(5)  RNN_K(6)  RNN_K(7)  RNN_K(8)                            \
        RNN_K(9)  RNN_K(10) RNN_K(11) RNN_K(12)                           \
        RNN_K(13) RNN_K(14) RNN_K(15)                                     \
        h1 = fast_tanh(a1 + a2);                                          \
        h2 = fast_tanh(b1 + b2);                                          \
    }

    #pragma unroll 1
    for (int tc = 0; tc < Tlen; tc += 4) {
        // prefetch next chunk (clamped on last iter; value unused then)
        const int tn = (tc + 4 < Tlen) ? (tc + 4) : tc;
        float4 xn = *(const float4*)(xr + tn);
        DO_STEP(xq.x)
        DO_STEP(xq.y)
        DO_STEP(xq.z)
        DO_STEP(xq.w)
        xq = xn;
    }
#undef DO_STEP
#undef RNN_K

    // out[row] = sum_p (h1*Wout[p] + h2*Wout[p+16]) + b_out, reduced over the
    // 16-lane group (xor offsets 1,2,4,8 stay inside the group).
    float v = fmaf(h1, Wout[p], h2 * Wout[p + 16]);
    v += __shfl_xor(v, 1, 64);
    v += __shfl_xor(v, 2, 64);
    v += __shfl_xor(v, 4, 64);
    v += __shfl_xor(v, 8, 64);
    if (p == 0) out[row] = v + b_out[0];
}

extern "C" void kernel_launch(void* const* d_in, const int* in_sizes, int n_in,
                              void* d_out, int out_size, void* d_ws, size_t ws_size,
                              hipStream_t stream) {
    const float* x     = (const float*)d_in[0];
    const float* Wxh   = (const float*)d_in[1];
    const float* b_xh  = (const float*)d_in[2];
    const float* Whh   = (const float*)d_in[3];
    const float* b_hh  = (const float*)d_in[4];
    const float* Wout  = (const float*)d_in[5];
    const float* b_out = (const float*)d_in[6];
    float* out = (float*)d_out;

    rnn_dpp_kernel<<<NBLOCKS, 256, 0, stream>>>(x, Wxh, b_xh, Whh, b_hh, Wout,
                                                b_out, out);
}